// Round 7
// baseline (306.937 us; speedup 1.0000x reference)
//
#include <hip/hip_runtime.h>

#define NTOK 49
#define CDIM 128
#define NH 4
#define NWIN 64

typedef unsigned short u16;
typedef unsigned int u32;
typedef __bf16 bf16x8 __attribute__((ext_vector_type(8)));
typedef float f32x4 __attribute__((ext_vector_type(4)));
typedef u16 u16x4 __attribute__((ext_vector_type(4)));

union Frag { u32 u[4]; bf16x8 v; };

// RNE f32->bf16 via compiler cast (1 VALU op).
__device__ __forceinline__ u16 f2bf(float f) {
  union { __bf16 h; u16 u; } c;
  c.h = (__bf16)f;
  return c.u;
}
__device__ __forceinline__ u32 pack2(float a, float b) {
  return (u32)f2bf(a) | ((u32)f2bf(b) << 16);
}
__device__ __forceinline__ bf16x8 ld8(const u16* p) { return *(const bf16x8*)p; }

// Convert C-layout register pairs (pairs over quad*4+{r,r+1}, two 16-tiles)
// into an MFMA A/B fragment k-slice. Verified by R0/R6 (V,P) and R3 (Q,K).
__device__ __forceinline__ void build_frag(u32 u[4], u32 x0, u32 y0, u32 x1, u32 y1,
                                           int quad, int ln) {
#pragma unroll
  for (int p = 0; p < 4; ++p) {
    int src = ((2 * (quad & 1) + (p >> 1)) << 4) | ln;
    int a0 = __shfl((int)((p & 1) ? y0 : x0), src);
    int a1 = __shfl((int)((p & 1) ? y1 : x1), src);
    u[p] = (u32)((quad < 2) ? a0 : a1);
  }
}

// ---------------- prep: transpose weights to bf16, build combined bias+mask ----
// ws layout (bytes): [0,98304) wqkvT bf16 (384x128)  [98304,131072) wprojT bf16 (128x128)
//                    [131072,131072+4MB) cmb f32 [win][h][q 64][m 64], -1e30 pads
__global__ void prep_kernel(const float* __restrict__ qkv_w,
                            const float* __restrict__ proj_w,
                            const float* __restrict__ bias_table,
                            const float* __restrict__ mask,
                            const int* __restrict__ rel_index,
                            u16* __restrict__ wqkvT,
                            u16* __restrict__ wprojT,
                            float* __restrict__ cmb) {
  int i = blockIdx.x * 256 + threadIdx.x;   // 1,048,576 threads
  if (i < 384 * 128) {
    int n = i >> 7, k = i & 127;
    wqkvT[i] = f2bf(qkv_w[k * 384 + n]);
  }
  if (i < 128 * 128) {
    int n = i >> 7, k = i & 127;
    wprojT[i] = f2bf(proj_w[k * 128 + n]);
  }
  int m = i & 63, q = (i >> 6) & 63, hh = (i >> 12) & 3, win = i >> 14;
  float v = -1e30f;
  if (q < NTOK && m < NTOK)
    v = bias_table[rel_index[q * NTOK + m] * NH + hh] + mask[(win * NTOK + q) * NTOK + m];
  cmb[i] = v;   // cmb[win][h][q][m], coalesced in m
}

// ---------------- fused window attention ----------------
// 4 waves = 4 heads. Q, K, V, P ALL register-resident:
//  * Q,K computed with SWAPPED mfma(bw, af) -> C-layout [ch][tok] packs
//    (verified R3); build_frag converts to S^T operand fragments.
//  * V computed normal -> [tok][d] packs (verified R0/R6).
//  * S^T = mfma(kf, qf): lane ln owns softmax row q; in-lane rowsum + 2
//    shfl_xor; normalized P packed in regs feeds PV via build_frag (R6).
// Q/K's LDS round-trip (128 ds_write_b16 + lgkm + 8 ds_read_b128 per wave)
// is replaced by 8 build_frags (64 ds_bpermute).
// launch_bounds(256,2): empirical VGPR cap = 256/arg2 = 128 (R4/R5 rule).
//
// LDS map (u16 units, 17408 total = 34816 B):
//   XB [0,8192): x bf16 64x128, xor-swizzled 16B chunks (read-only after A)
//   AO [8192 + h*2304): per-head attention output 64x36 (d=0..31), phase E
#define AOFF 8192

__device__ __forceinline__ int xsw(int row, int col) {
  return (row << 7) + ((((col >> 3) ^ (row & 15)) << 3) | (col & 7));
}

__global__ __launch_bounds__(256, 2)
void swin_fused(const float* __restrict__ x, const float* __restrict__ qkv_b,
                const float* __restrict__ proj_b, const u16* __restrict__ wqkvT,
                const u16* __restrict__ wprojT, const float* __restrict__ cmb,
                float* __restrict__ out) {
  __shared__ u16 lds[17408];
  const int tid  = threadIdx.x;
  const int w    = tid >> 6;       // wave = head
  const int lane = tid & 63;
  const int ln   = lane & 15;
  const int quad = lane >> 4;
  const int b    = blockIdx.x;
  const int win  = b & (NWIN - 1);
  const float scale = 0.17677669529663687f;  // 32^-0.5

  // ---- Phase A: x -> LDS bf16 (rows 49..63 zeroed), coalesced float4 loads ----
  {
    const float4* x4 = (const float4*)(x + (size_t)b * (NTOK * CDIM));
    for (int i = tid; i < (NTOK * CDIM) / 4; i += 256) {
      float4 f = x4[i];
      int e = i << 2;
      int row = e >> 7, col = e & 127;
      u16x4 v;
      v[0] = f2bf(f.x); v[1] = f2bf(f.y); v[2] = f2bf(f.z); v[3] = f2bf(f.w);
      *(u16x4*)&lds[xsw(row, col)] = v;
    }
    for (int i = tid; i < (15 * CDIM) / 4; i += 256) {
      int e = i << 2;
      int row = NTOK + (e >> 7), col = e & 127;
      u16x4 v = {0, 0, 0, 0};
      *(u16x4*)&lds[xsw(row, col)] = v;
    }
  }
  __syncthreads();   // #1: XB ready

  // ---- Phase B: Q,K (swapped) and V (normal) -> registers ----
  u32 qx[4][2], qy[4][2], kx[4][2], ky[4][2], vbx[4][2], vby[4][2];
  {
#pragma unroll
    for (int tm = 0; tm < 4; ++tm) {
      bf16x8 af[4];
#pragma unroll
      for (int ks = 0; ks < 4; ++ks)
        af[ks] = ld8(&lds[xsw(tm * 16 + ln, ks * 32 + quad * 8)]);

      // Q (sect 0) and K (sect 1): swapped operands -> [ch][tok] C-layout
#pragma unroll
      for (int sect = 0; sect < 2; ++sect) {
#pragma unroll
        for (int tc = 0; tc < 2; ++tc) {
          int colb = sect * 128 + w * 32 + tc * 16;
          bf16x8 bw[4];
#pragma unroll
          for (int ks = 0; ks < 4; ++ks)
            bw[ks] = ld8(wqkvT + (colb + ln) * 128 + ks * 32 + quad * 8);
          f32x4 cb4 = *(const f32x4*)&qkv_b[colb + quad * 4];
          f32x4 acc = {0.f, 0.f, 0.f, 0.f};
#pragma unroll
          for (int ks = 0; ks < 4; ++ks)
            acc = __builtin_amdgcn_mfma_f32_16x16x32_bf16(bw[ks], af[ks], acc, 0, 0, 0);
          if (sect == 0) {
            qx[tm][tc] = pack2((acc[0] + cb4[0]) * scale, (acc[1] + cb4[1]) * scale);
            qy[tm][tc] = pack2((acc[2] + cb4[2]) * scale, (acc[3] + cb4[3]) * scale);
          } else {
            kx[tm][tc] = pack2(acc[0] + cb4[0], acc[1] + cb4[1]);
            ky[tm][tc] = pack2(acc[2] + cb4[2], acc[3] + cb4[3]);
          }
        }
      }
      // V: normal orientation -> [tok][d] C-layout
#pragma unroll
      for (int tc = 0; tc < 2; ++tc) {
        int colg = 256 + w * 32 + tc * 16 + ln;
        bf16x8 bw[4];
#pragma unroll
        for (int ks = 0; ks < 4; ++ks)
          bw[ks] = ld8(wqkvT + colg * 128 + ks * 32 + quad * 8);
        float cb = qkv_b[colg];
        f32x4 acc = {0.f, 0.f, 0.f, 0.f};
#pragma unroll
        for (int ks = 0; ks < 4; ++ks)
          acc = __builtin_amdgcn_mfma_f32_16x16x32_bf16(af[ks], bw[ks], acc, 0, 0, 0);
        vbx[tm][tc] = pack2(acc[0] + cb, acc[1] + cb);
        vby[tm][tc] = pack2(acc[2] + cb, acc[3] + cb);
      }
    }
  }
  // no barrier: phases C/D are pure register/shuffle work

  // ---- Phase C+D: fragments via shuffle; S^T; softmax; PV; AO -> LDS ----
  {
    // Build V and K fragments first so the packed arrays die early.
    Frag bv[2][2];
#pragma unroll
    for (int ks = 0; ks < 2; ++ks)
#pragma unroll
      for (int tc = 0; tc < 2; ++tc)
        build_frag(bv[ks][tc].u, vbx[2 * ks][tc], vby[2 * ks][tc],
                   vbx[2 * ks + 1][tc], vby[2 * ks + 1][tc], quad, ln);
    Frag kf[4];
#pragma unroll
    for (int tn = 0; tn < 4; ++tn)
      build_frag(kf[tn].u, kx[tn][0], ky[tn][0], kx[tn][1], ky[tn][1], quad, ln);

    const float* cbp = cmb + ((size_t)((win << 2) | w) << 12);
#pragma unroll
    for (int tm = 0; tm < 4; ++tm) {
      Frag qf;
      build_frag(qf.u, qx[tm][0], qy[tm][0], qx[tm][1], qy[tm][1], quad, ln);
      f32x4 s[4];   // s[tn][r] = S[m=tn*16+quad*4+r][q=tm*16+ln]
#pragma unroll
      for (int tn = 0; tn < 4; ++tn) {
        f32x4 z = {0.f, 0.f, 0.f, 0.f};
        s[tn] = __builtin_amdgcn_mfma_f32_16x16x32_bf16(kf[tn].v, qf.v, z, 0, 0, 0);
      }

      float e[4][4];
      float tsum = 0.f;
#pragma unroll
      for (int tn = 0; tn < 4; ++tn) {
        f32x4 c4 = *(const f32x4*)&cbp[(tm * 16 + ln) * 64 + tn * 16 + quad * 4];
#pragma unroll
        for (int r = 0; r < 4; ++r)
          e[tn][r] = __expf(s[tn][r] + c4[r]);
        tsum += (e[tn][0] + e[tn][1]) + (e[tn][2] + e[tn][3]);
      }
      tsum += __shfl_xor(tsum, 16);
      tsum += __shfl_xor(tsum, 32);
      float iv = 1.0f / fmaxf(tsum, 1e-30f);   // pad q-rows: e==0 -> o=0 anyway

      u32 px[4], py[4];
#pragma unroll
      for (int tn = 0; tn < 4; ++tn) {
        px[tn] = pack2(e[tn][0] * iv, e[tn][1] * iv);
        py[tn] = pack2(e[tn][2] * iv, e[tn][3] * iv);
      }

      f32x4 o[2];
#pragma unroll
      for (int tc = 0; tc < 2; ++tc) { f32x4 z = {0.f,0.f,0.f,0.f}; o[tc] = z; }
#pragma unroll
      for (int ks = 0; ks < 2; ++ks) {
        Frag pa;
        build_frag(pa.u, px[2 * ks], py[2 * ks], px[2 * ks + 1], py[2 * ks + 1], quad, ln);
#pragma unroll
        for (int tc = 0; tc < 2; ++tc)
          o[tc] = __builtin_amdgcn_mfma_f32_16x16x32_bf16(pa.v, bv[ks][tc].v, o[tc], 0, 0, 0);
      }

      // AO store (already normalized)
      int row0 = tm * 16 + quad * 4;
#pragma unroll
      for (int tc = 0; tc < 2; ++tc)
#pragma unroll
        for (int r = 0; r < 4; ++r)
          lds[AOFF + w * 2304 + (row0 + r) * 36 + tc * 16 + ln] = f2bf(o[tc][r]);
    }
  }
  __syncthreads();   // #2: AO of all heads visible

  // ---- Phase E: out = AO @ proj_w + proj_b ----
  {
    bf16x8 aof[4][4];
#pragma unroll
    for (int tm = 0; tm < 4; ++tm)
#pragma unroll
      for (int ks = 0; ks < 4; ++ks)
        aof[tm][ks] = ld8(&lds[AOFF + ks * 2304 + (tm * 16 + ln) * 36 + quad * 8]);
#pragma unroll
    for (int tj = 0; tj < 2; ++tj) {
      int colg = w * 32 + tj * 16 + ln;
      bf16x8 bw[4];
#pragma unroll
      for (int ks = 0; ks < 4; ++ks)
        bw[ks] = ld8(wprojT + colg * 128 + ks * 32 + quad * 8);
      float pb = proj_b[colg];
#pragma unroll
      for (int tm = 0; tm < 4; ++tm) {
        f32x4 acc = {0.f, 0.f, 0.f, 0.f};
#pragma unroll
        for (int ks = 0; ks < 4; ++ks)
          acc = __builtin_amdgcn_mfma_f32_16x16x32_bf16(aof[tm][ks], bw[ks], acc, 0, 0, 0);
        int row0 = tm * 16 + quad * 4;
#pragma unroll
        for (int r = 0; r < 4; ++r) {
          int rr = row0 + r;
          if (rr < NTOK)
            out[((size_t)b * NTOK + rr) * CDIM + colg] = acc[r] + pb;
        }
      }
    }
  }
}

extern "C" void kernel_launch(void* const* d_in, const int* in_sizes, int n_in,
                              void* d_out, int out_size, void* d_ws, size_t ws_size,
                              hipStream_t stream) {
  const float* x          = (const float*)d_in[0];
  const float* qkv_w      = (const float*)d_in[1];
  const float* qkv_b      = (const float*)d_in[2];
  const float* proj_w     = (const float*)d_in[3];
  const float* proj_b     = (const float*)d_in[4];
  const float* bias_table = (const float*)d_in[5];
  const float* mask       = (const float*)d_in[6];
  const int*   rel_index  = (const int*)d_in[7];

  u16*   wqkvT  = (u16*)d_ws;
  u16*   wprojT = wqkvT + 384 * 128;
  float* cmb    = (float*)((char*)d_ws + 131072);

  const int Bt = in_sizes[0] / (NTOK * CDIM);   // 4096

  prep_kernel<<<4096, 256, 0, stream>>>(qkv_w, proj_w, bias_table, mask, rel_index,
                                        wqkvT, wprojT, cmb);
  swin_fused<<<Bt, 256, 0, stream>>>(x, qkv_b, proj_b, wqkvT, wprojT, cmb, (float*)d_out);
}

// Round 8
// 286.986 us; speedup vs baseline: 1.0695x; 1.0695x over previous
//
#include <hip/hip_runtime.h>

#define NTOK 49
#define CDIM 128
#define NH 4
#define NWIN 64

typedef unsigned short u16;
typedef unsigned int u32;
typedef __bf16 bf16x8 __attribute__((ext_vector_type(8)));
typedef float f32x4 __attribute__((ext_vector_type(4)));
typedef u16 u16x4 __attribute__((ext_vector_type(4)));

union Frag { u32 u[4]; bf16x8 v; };

// RNE f32->bf16 via compiler cast (1 VALU op).
__device__ __forceinline__ u16 f2bf(float f) {
  union { __bf16 h; u16 u; } c;
  c.h = (__bf16)f;
  return c.u;
}
__device__ __forceinline__ u32 pack2(float a, float b) {
  return (u32)f2bf(a) | ((u32)f2bf(b) << 16);
}
__device__ __forceinline__ bf16x8 ld8(const u16* p) { return *(const bf16x8*)p; }

// Convert C-layout register pairs (pairs over quad*4+{r,r+1}, two 16-tiles)
// into an MFMA A/B fragment k-slice. Verified by R0/R6 (V, P paths).
__device__ __forceinline__ void build_frag(u32 u[4], u32 x0, u32 y0, u32 x1, u32 y1,
                                           int quad, int ln) {
#pragma unroll
  for (int p = 0; p < 4; ++p) {
    int src = ((2 * (quad & 1) + (p >> 1)) << 4) | ln;
    int a0 = __shfl((int)((p & 1) ? y0 : x0), src);
    int a1 = __shfl((int)((p & 1) ? y1 : x1), src);
    u[p] = (u32)((quad < 2) ? a0 : a1);
  }
}

// ---------------- prep: transpose weights to bf16, build combined bias+mask ----
// ws layout (bytes): [0,98304) wqkvT bf16 (384x128)  [98304,131072) wprojT bf16 (128x128)
//                    [131072,131072+4MB) cmb f32 [win][h][q 64][m 64], -1e30 pads
// cmb is [q][m] because S is computed transposed (lane owns softmax row q).
__global__ void prep_kernel(const float* __restrict__ qkv_w,
                            const float* __restrict__ proj_w,
                            const float* __restrict__ bias_table,
                            const float* __restrict__ mask,
                            const int* __restrict__ rel_index,
                            u16* __restrict__ wqkvT,
                            u16* __restrict__ wprojT,
                            float* __restrict__ cmb) {
  int i = blockIdx.x * 256 + threadIdx.x;   // 1,048,576 threads
  if (i < 384 * 128) {
    int n = i >> 7, k = i & 127;
    wqkvT[i] = f2bf(qkv_w[k * 384 + n]);
  }
  if (i < 128 * 128) {
    int n = i >> 7, k = i & 127;
    wprojT[i] = f2bf(proj_w[k * 128 + n]);
  }
  int m = i & 63, q = (i >> 6) & 63, hh = (i >> 12) & 3, win = i >> 14;
  float v = -1e30f;
  if (q < NTOK && m < NTOK)
    v = bias_table[rel_index[q * NTOK + m] * NH + hh] + mask[(win * NTOK + q) * NTOK + m];
  cmb[i] = v;   // cmb[win][h][q][m], coalesced in m
}

// ---------------- fused window attention ----------------
// R6 structure (best verified: 150us): 4 waves = 4 heads; Q,K staged in LDS;
// V in registers; S computed TRANSPOSED (mfma(K,Q)) so softmax rows are
// lane-local; P stays in registers and feeds PV via build_frag.
// R8 change: Q/K/AO regions OVERLAY XB. XB is dead after the af[4][4]
// fragment loads at the top of phase B (one extra barrier makes this safe
// across waves), so the regions start at offset 0. LDS 53248 -> 36864 B
// => 4 blocks/CU (occupancy cap 37.5% -> 50%).
// R7 lesson: occupancy DOES bind below ~30% (VGPR+AGPR pressure dropped it
// to 21% -> 174us); R6's 72-VGPR footprint + 36864B LDS supports 16 waves/CU.
//
// LDS map (u16 units, 18432 total = 36864 B):
//   XB [0,8192): x bf16 64x128, xor-swizzled (live phase A .. af loads)
//   R(h) = h*4608 (live after barrier #1b, overlays XB):
//     Q : R(h)        + row*36 + d   (64x36, d=0..31)
//     K : R(h) + 2304 + row*36 + d
//     AO: R(h)        + row*36 + d   -- overlays Q after phase-C reads
#define RGN(h) ((h) * 4608)

__device__ __forceinline__ int xsw(int row, int col) {
  return (row << 7) + ((((col >> 3) ^ (row & 15)) << 3) | (col & 7));
}

__global__ __launch_bounds__(256, 2)
void swin_fused(const float* __restrict__ x, const float* __restrict__ qkv_b,
                const float* __restrict__ proj_b, const u16* __restrict__ wqkvT,
                const u16* __restrict__ wprojT, const float* __restrict__ cmb,
                float* __restrict__ out) {
  __shared__ u16 lds[18432];
  const int tid  = threadIdx.x;
  const int w    = tid >> 6;       // wave = head
  const int lane = tid & 63;
  const int ln   = lane & 15;
  const int quad = lane >> 4;
  const int b    = blockIdx.x;
  const int win  = b & (NWIN - 1);
  const float scale = 0.17677669529663687f;  // 32^-0.5

  // ---- Phase A: x -> LDS bf16 (rows 49..63 zeroed), coalesced float4 loads ----
  {
    const float4* x4 = (const float4*)(x + (size_t)b * (NTOK * CDIM));
    for (int i = tid; i < (NTOK * CDIM) / 4; i += 256) {
      float4 f = x4[i];
      int e = i << 2;
      int row = e >> 7, col = e & 127;
      u16x4 v;
      v[0] = f2bf(f.x); v[1] = f2bf(f.y); v[2] = f2bf(f.z); v[3] = f2bf(f.w);
      *(u16x4*)&lds[xsw(row, col)] = v;
    }
    for (int i = tid; i < (15 * CDIM) / 4; i += 256) {
      int e = i << 2;
      int row = NTOK + (e >> 7), col = e & 127;
      u16x4 v = {0, 0, 0, 0};
      *(u16x4*)&lds[xsw(row, col)] = v;
    }
  }
  __syncthreads();   // #1: XB ready

  // ---- Phase B: wave w computes q/k/v of head w. Q,K -> LDS (overlaying XB); V -> regs ----
  u32 vbx[4][2], vby[4][2];   // packed bf16 V: tokens (4q+0,4q+1)/(4q+2,4q+3), [tok-tile][dim-tile]
  {
    bf16x8 af[4][4];
#pragma unroll
    for (int tm = 0; tm < 4; ++tm)
#pragma unroll
      for (int ks = 0; ks < 4; ++ks)
        af[tm][ks] = ld8(&lds[xsw(tm * 16 + ln, ks * 32 + quad * 8)]);
    __syncthreads();   // #1b: all waves hold x in regs -> XB dead, regions may overlay

#pragma unroll
    for (int tl = 0; tl < 6; ++tl) {
      int sect = tl >> 1, tc = tl & 1;
      int colg = sect * 128 + w * 32 + tc * 16 + ln;
      bf16x8 bw[4];
#pragma unroll
      for (int ks = 0; ks < 4; ++ks)
        bw[ks] = ld8(wqkvT + colg * 128 + ks * 32 + quad * 8);
      float cb = qkv_b[colg];
#pragma unroll
      for (int tm = 0; tm < 4; ++tm) {
        f32x4 acc = {0.f, 0.f, 0.f, 0.f};
#pragma unroll
        for (int ks = 0; ks < 4; ++ks)
          acc = __builtin_amdgcn_mfma_f32_16x16x32_bf16(af[tm][ks], bw[ks], acc, 0, 0, 0);
        int row0 = tm * 16 + quad * 4;   // C-layout: col=ln, row=quad*4+r
        if (sect == 0) {
#pragma unroll
          for (int r = 0; r < 4; ++r)
            lds[RGN(w) + (row0 + r) * 36 + tc * 16 + ln] = f2bf((acc[r] + cb) * scale);
        } else if (sect == 1) {
#pragma unroll
          for (int r = 0; r < 4; ++r)
            lds[RGN(w) + 2304 + (row0 + r) * 36 + tc * 16 + ln] = f2bf(acc[r] + cb);
        } else {
          vbx[tm][tc] = pack2(acc[0] + cb, acc[1] + cb);
          vby[tm][tc] = pack2(acc[2] + cb, acc[3] + cb);
        }
      }
    }
  }
  // no barrier: phases C/D read only wave-private regions + registers

  // ---- Phase C+D: S^T = mfma(K,Q); bias+exp; lane-local rowsum; P in regs -> PV ----
  {
    bf16x8 aq[4], bk[4];
#pragma unroll
    for (int t = 0; t < 4; ++t) {
      aq[t] = ld8(&lds[RGN(w) + (t * 16 + ln) * 36 + quad * 8]);
      bk[t] = ld8(&lds[RGN(w) + 2304 + (t * 16 + ln) * 36 + quad * 8]);
    }
    f32x4 s[4][4];   // s[tm][tn][r] = S[m=tn*16+quad*4+r][q=tm*16+ln]
#pragma unroll
    for (int tn = 0; tn < 4; ++tn)
#pragma unroll
      for (int tm = 0; tm < 4; ++tm) {
        f32x4 z = {0.f, 0.f, 0.f, 0.f};
        s[tm][tn] = __builtin_amdgcn_mfma_f32_16x16x32_bf16(bk[tn], aq[tm], z, 0, 0, 0);
      }

    // V B-fragments (register shuffle)
    Frag bv[2][2];
#pragma unroll
    for (int ks = 0; ks < 2; ++ks)
#pragma unroll
      for (int tc = 0; tc < 2; ++tc)
        build_frag(bv[ks][tc].u, vbx[2 * ks][tc], vby[2 * ks][tc],
                   vbx[2 * ks + 1][tc], vby[2 * ks + 1][tc], quad, ln);

    const float* cbp = cmb + ((size_t)((win << 2) | w) << 12);
#pragma unroll
    for (int tm = 0; tm < 4; ++tm) {
      // bias + exp over this q-column's 64 m values (16 in-lane x 4 quads)
      float e[4][4];
      float tsum = 0.f;
#pragma unroll
      for (int tn = 0; tn < 4; ++tn) {
        f32x4 c4 = *(const f32x4*)&cbp[(tm * 16 + ln) * 64 + tn * 16 + quad * 4];
#pragma unroll
        for (int r = 0; r < 4; ++r)
          e[tn][r] = __expf(s[tm][tn][r] + c4[r]);
        tsum += (e[tn][0] + e[tn][1]) + (e[tn][2] + e[tn][3]);
      }
      tsum += __shfl_xor(tsum, 16);
      tsum += __shfl_xor(tsum, 32);
      float iv = 1.0f / fmaxf(tsum, 1e-30f);   // pad q-rows: sum=0 -> o=0 anyway

      // normalized P, packed over m-pairs (same structure as V packs)
      u32 px[4], py[4];
#pragma unroll
      for (int tn = 0; tn < 4; ++tn) {
        px[tn] = pack2(e[tn][0] * iv, e[tn][1] * iv);
        py[tn] = pack2(e[tn][2] * iv, e[tn][3] * iv);
      }

      // PV for this q-tile
      f32x4 o[2];
#pragma unroll
      for (int tc = 0; tc < 2; ++tc) { f32x4 z = {0.f,0.f,0.f,0.f}; o[tc] = z; }
#pragma unroll
      for (int ks = 0; ks < 2; ++ks) {
        Frag pa;
        build_frag(pa.u, px[2 * ks], py[2 * ks], px[2 * ks + 1], py[2 * ks + 1], quad, ln);
#pragma unroll
        for (int tc = 0; tc < 2; ++tc)
          o[tc] = __builtin_amdgcn_mfma_f32_16x16x32_bf16(pa.v, bv[ks][tc].v, o[tc], 0, 0, 0);
      }

      // AO store (normalized; overlays Q region -- aq reads are done)
      int row0 = tm * 16 + quad * 4;
#pragma unroll
      for (int tc = 0; tc < 2; ++tc)
#pragma unroll
        for (int r = 0; r < 4; ++r)
          lds[RGN(w) + (row0 + r) * 36 + tc * 16 + ln] = f2bf(o[tc][r]);
    }
  }
  __syncthreads();   // #2: AO of all heads visible

  // ---- Phase E: out = AO @ proj_w + proj_b ----
  {
    bf16x8 aof[4][4];
#pragma unroll
    for (int tm = 0; tm < 4; ++tm)
#pragma unroll
      for (int ks = 0; ks < 4; ++ks)
        aof[tm][ks] = ld8(&lds[RGN(ks) + (tm * 16 + ln) * 36 + quad * 8]);
#pragma unroll
    for (int tj = 0; tj < 2; ++tj) {
      int colg = w * 32 + tj * 16 + ln;
      bf16x8 bw[4];
#pragma unroll
      for (int ks = 0; ks < 4; ++ks)
        bw[ks] = ld8(wprojT + colg * 128 + ks * 32 + quad * 8);
      float pb = proj_b[colg];
#pragma unroll
      for (int tm = 0; tm < 4; ++tm) {
        f32x4 acc = {0.f, 0.f, 0.f, 0.f};
#pragma unroll
        for (int ks = 0; ks < 4; ++ks)
          acc = __builtin_amdgcn_mfma_f32_16x16x32_bf16(aof[tm][ks], bw[ks], acc, 0, 0, 0);
        int row0 = tm * 16 + quad * 4;
#pragma unroll
        for (int r = 0; r < 4; ++r) {
          int rr = row0 + r;
          if (rr < NTOK)
            out[((size_t)b * NTOK + rr) * CDIM + colg] = acc[r] + pb;
        }
      }
    }
  }
}

extern "C" void kernel_launch(void* const* d_in, const int* in_sizes, int n_in,
                              void* d_out, int out_size, void* d_ws, size_t ws_size,
                              hipStream_t stream) {
  const float* x          = (const float*)d_in[0];
  const float* qkv_w      = (const float*)d_in[1];
  const float* qkv_b      = (const float*)d_in[2];
  const float* proj_w     = (const float*)d_in[3];
  const float* proj_b     = (const float*)d_in[4];
  const float* bias_table = (const float*)d_in[5];
  const float* mask       = (const float*)d_in[6];
  const int*   rel_index  = (const int*)d_in[7];

  u16*   wqkvT  = (u16*)d_ws;
  u16*   wprojT = wqkvT + 384 * 128;
  float* cmb    = (float*)((char*)d_ws + 131072);

  const int Bt = in_sizes[0] / (NTOK * CDIM);   // 4096

  prep_kernel<<<4096, 256, 0, stream>>>(qkv_w, proj_w, bias_table, mask, rel_index,
                                        wqkvT, wprojT, cmb);
  swin_fused<<<Bt, 256, 0, stream>>>(x, qkv_b, proj_b, wqkvT, wprojT, cmb, (float*)d_out);
}